// Round 1
// baseline (706.356 us; speedup 1.0000x reference)
//
#include <hip/hip_runtime.h>
#include <math.h>

typedef float4 f4;

static constexpr int kB  = 8;
static constexpr int kT  = 4096;
static constexpr int kD  = 1024;
static constexpr int kH  = 64;
static constexpr int kC  = 64;            // chunk length
static constexpr int kNC = kT / kC;       // 64 chunks per batch
static constexpr long kBT = (long)kB * kT;

__device__ __forceinline__ float phi_f(float x) {
    // phi(x) = elu(x) + 1 = x+1 (x>0) else exp(x)
    return x > 0.0f ? x + 1.0f : __expf(x);
}

#define LD4F(dst, src) { f4 _t_ = *(const f4*)(src); (dst)[0]=_t_.x; (dst)[1]=_t_.y; (dst)[2]=_t_.z; (dst)[3]=_t_.w; }

// ---------------------------------------------------------------------------
// K1: q = phi(x Wq), k = phi(x Wk), v = x Wv.   M=32768, K=1024, N=3x64.
// BM=128 rows/block, BK=32, 256 threads, per-thread 8 rows x (4 cols x 3 mats).
// ---------------------------------------------------------------------------
__global__ __launch_bounds__(256)
void k1_qkv(const float* __restrict__ x, const float* __restrict__ Wq,
            const float* __restrict__ Wk, const float* __restrict__ Wv,
            float* __restrict__ q, float* __restrict__ k, float* __restrict__ v)
{
    __shared__ float As[32][132];   // x tile transposed [k][row], +4 pad
    __shared__ float Ws[32][192];   // [k][mat*64+col]

    const int t  = threadIdx.x;
    const int rg = t >> 4;          // 16 groups x 8 rows
    const int cg = t & 15;          // 16 groups x 4 cols per mat
    const int r0 = rg * 8;
    const int c0 = cg * 4;
    const long mb = (long)blockIdx.x * 128;

    float acc[3][8][4];
    #pragma unroll
    for (int m = 0; m < 3; ++m)
        #pragma unroll
        for (int r = 0; r < 8; ++r)
            #pragma unroll
            for (int c = 0; c < 4; ++c) acc[m][r][c] = 0.0f;

    const float* Wm[3] = {Wq, Wk, Wv};

    for (int k0 = 0; k0 < kD; k0 += 32) {
        #pragma unroll
        for (int i = 0; i < 4; ++i) {           // stage x tile (transposed)
            int fi  = t + i * 256;              // 0..1023 f4 index
            int row = fi >> 3;
            int kc  = (fi & 7) * 4;
            f4 val = *(const f4*)&x[(mb + row) * kD + k0 + kc];
            As[kc + 0][row] = val.x;
            As[kc + 1][row] = val.y;
            As[kc + 2][row] = val.z;
            As[kc + 3][row] = val.w;
        }
        #pragma unroll
        for (int m = 0; m < 3; ++m) {           // stage W tiles
            #pragma unroll
            for (int i = 0; i < 2; ++i) {
                int fi = t + i * 256;           // 0..511
                int kr = fi >> 4;
                int cc = (fi & 15) * 4;
                *(f4*)&Ws[kr][m * 64 + cc] =
                    *(const f4*)&Wm[m][(long)(k0 + kr) * kH + cc];
            }
        }
        __syncthreads();
        #pragma unroll 8
        for (int kk = 0; kk < 32; ++kk) {
            float av[8];
            LD4F(av,     &As[kk][r0]);
            LD4F(av + 4, &As[kk][r0 + 4]);
            #pragma unroll
            for (int m = 0; m < 3; ++m) {
                float wv[4];
                LD4F(wv, &Ws[kk][m * 64 + c0]);
                #pragma unroll
                for (int r = 0; r < 8; ++r)
                    #pragma unroll
                    for (int c = 0; c < 4; ++c)
                        acc[m][r][c] += av[r] * wv[c];
            }
        }
        __syncthreads();
    }
    float* outp[3] = {q, k, v};
    #pragma unroll
    for (int m = 0; m < 3; ++m) {
        #pragma unroll
        for (int r = 0; r < 8; ++r) {
            f4 val;
            if (m < 2) {
                val.x = phi_f(acc[m][r][0]); val.y = phi_f(acc[m][r][1]);
                val.z = phi_f(acc[m][r][2]); val.w = phi_f(acc[m][r][3]);
            } else {
                val.x = acc[m][r][0]; val.y = acc[m][r][1];
                val.z = acc[m][r][2]; val.w = acc[m][r][3];
            }
            *(f4*)&outp[m][(mb + r0 + r) * kH + c0] = val;
        }
    }
}

// ---------------------------------------------------------------------------
// K2: per-chunk state  Sc[i][j] = sum_tau k[tau][i] v[tau][j],  zc[i] = sum k.
// One block per (b, chunk).
// ---------------------------------------------------------------------------
__global__ __launch_bounds__(256)
void k2_state(const float* __restrict__ k, const float* __restrict__ v,
              float* __restrict__ Sc, float* __restrict__ zc)
{
    __shared__ float Ks2[64][64];
    __shared__ float Vs2[64][64];
    const int t = threadIdx.x;
    const long bc = blockIdx.x;           // b*NC + c
    const long rowbase = bc * kC;         // = b*T + c*C

    #pragma unroll
    for (int i = 0; i < 4; ++i) {
        int fi  = t + i * 256;
        int tau = fi >> 4;
        int cc  = (fi & 15) * 4;
        *(f4*)&Ks2[tau][cc] = *(const f4*)&k[(rowbase + tau) * kH + cc];
        *(f4*)&Vs2[tau][cc] = *(const f4*)&v[(rowbase + tau) * kH + cc];
    }
    __syncthreads();

    const int i  = t >> 2;
    const int j0 = (t & 3) * 16;
    float acc[16];
    #pragma unroll
    for (int c = 0; c < 16; ++c) acc[c] = 0.0f;
    float zacc = 0.0f;

    for (int tau = 0; tau < 64; ++tau) {
        float kv = Ks2[tau][i];
        zacc += kv;
        #pragma unroll
        for (int c = 0; c < 4; ++c) {
            float vv[4];
            LD4F(vv, &Vs2[tau][j0 + c * 4]);
            #pragma unroll
            for (int e = 0; e < 4; ++e) acc[c * 4 + e] += kv * vv[e];
        }
    }
    float* scp = Sc + bc * (kH * kH) + i * kH + j0;
    #pragma unroll
    for (int c = 0; c < 4; ++c) {
        f4 val; val.x = acc[c*4]; val.y = acc[c*4+1]; val.z = acc[c*4+2]; val.w = acc[c*4+3];
        *(f4*)&scp[c * 4] = val;
    }
    if ((t & 3) == 0) zc[bc * kH + i] = zacc;
}

// ---------------------------------------------------------------------------
// K3: exclusive prefix over chunks.  32768 independent chains for S (len 64),
// 512 chains for z.  All-loads-then-prefix-then-stores keeps latency hidden.
// ---------------------------------------------------------------------------
__global__ __launch_bounds__(256)
void k3_prefix(const float* __restrict__ Sc, float* __restrict__ Sp,
               const float* __restrict__ zc, float* __restrict__ zp)
{
    const int t = threadIdx.x;
    const int blk = blockIdx.x;
    if (blk < 128) {
        int g = blk * 256 + t;             // 0..32767
        int b = g >> 12;
        int rem = g & 4095;
        const float* src = Sc + (long)b * kNC * kH * kH + rem;
        float*       dst = Sp + (long)b * kNC * kH * kH + rem;
        float vals[kNC];
        #pragma unroll
        for (int c = 0; c < kNC; ++c) vals[c] = src[c * (kH * kH)];
        float run = 0.0f;
        #pragma unroll
        for (int c = 0; c < kNC; ++c) { float nv = vals[c]; vals[c] = run; run += nv; }
        #pragma unroll
        for (int c = 0; c < kNC; ++c) dst[c * (kH * kH)] = vals[c];
    } else {
        int g = (blk - 128) * 256 + t;     // 0..511
        int b = g >> 6;
        int i = g & 63;
        const float* src = zc + (long)b * kNC * kH + i;
        float*       dst = zp + (long)b * kNC * kH + i;
        float vals[kNC];
        #pragma unroll
        for (int c = 0; c < kNC; ++c) vals[c] = src[c * kH];
        float run = 0.0f;
        #pragma unroll
        for (int c = 0; c < kNC; ++c) { float nv = vals[c]; vals[c] = run; run += nv; }
        #pragma unroll
        for (int c = 0; c < kNC; ++c) dst[c * kH] = vals[c];
    }
}

// ---------------------------------------------------------------------------
// K4: per-chunk output.
//  o[tau][i] = sum_j Sp[i][j] q[tau][j]  +  sum_{tau'<=tau} (v_tau'.q_tau) k_tau'[i]
//  d[tau]    = q_tau . (zp + cumsum_k[tau]);   out = o / max(d,1e-6)
// LDS: QT (Q^T), KsS (K row-major, XOR-swizzled), VT (V^T -> P^T -> Sp^T).
// ---------------------------------------------------------------------------
__global__ __launch_bounds__(256)
void k4_chunkout(const float* __restrict__ q, const float* __restrict__ k,
                 const float* __restrict__ v, const float* __restrict__ Sp,
                 const float* __restrict__ zp, float* __restrict__ o)
{
    __shared__ float QT[64 * 64];
    __shared__ float KsS[64 * 64];
    __shared__ float VT[64 * 64];
    __shared__ float zps[64];
    __shared__ float ds[64];

    const int t = threadIdx.x;
    const long bc = blockIdx.x;
    const long rowbase = bc * kC;

    // ---- stage Q^T, V^T, K (swizzled) ----
    #pragma unroll
    for (int ii = 0; ii < 4; ++ii) {
        int fi  = t + ii * 256;
        int tau = fi >> 4;
        int c4  = fi & 15;
        f4 qv = *(const f4*)&q[(rowbase + tau) * kH + c4 * 4];
        QT[(c4 * 4 + 0) * 64 + tau] = qv.x;
        QT[(c4 * 4 + 1) * 64 + tau] = qv.y;
        QT[(c4 * 4 + 2) * 64 + tau] = qv.z;
        QT[(c4 * 4 + 3) * 64 + tau] = qv.w;
        f4 vv = *(const f4*)&v[(rowbase + tau) * kH + c4 * 4];
        VT[(c4 * 4 + 0) * 64 + tau] = vv.x;
        VT[(c4 * 4 + 1) * 64 + tau] = vv.y;
        VT[(c4 * 4 + 2) * 64 + tau] = vv.z;
        VT[(c4 * 4 + 3) * 64 + tau] = vv.w;
        f4 kv = *(const f4*)&k[(rowbase + tau) * kH + c4 * 4];
        *(f4*)&KsS[tau * 64 + 4 * (c4 ^ (tau & 15))] = kv;
    }
    if (t < 16) {
        *(f4*)&zps[t * 4] = *(const f4*)&zp[bc * kH + t * 4];
    }
    __syncthreads();

    const int tg   = t & 15;
    const int ig   = t >> 4;
    const int tau0 = tg * 4;   // 4 output rows (tau)
    const int ip0  = ig * 4;   // 4 tau' (ph2) / 4 i (ph3,ph4)

    // ---- phase 2: P[tau][tau'] = q_tau . v_tau' ----
    float pv[4][4];
    #pragma unroll
    for (int a = 0; a < 4; ++a)
        #pragma unroll
        for (int b2 = 0; b2 < 4; ++b2) pv[a][b2] = 0.0f;
    for (int xx = 0; xx < 64; ++xx) {
        float q4[4], v4[4];
        LD4F(q4, &QT[xx * 64 + tau0]);
        LD4F(v4, &VT[xx * 64 + ip0]);
        #pragma unroll
        for (int e1 = 0; e1 < 4; ++e1)
            #pragma unroll
            for (int e0 = 0; e0 < 4; ++e0) pv[e1][e0] += v4[e1] * q4[e0];
    }
    __syncthreads();
    // write masked P^T into VT space: Pt[tau'][tau]
    #pragma unroll
    for (int e1 = 0; e1 < 4; ++e1) {
        int tp = ip0 + e1;
        f4 w;
        w.x = (tp <= tau0 + 0) ? pv[e1][0] : 0.0f;
        w.y = (tp <= tau0 + 1) ? pv[e1][1] : 0.0f;
        w.z = (tp <= tau0 + 2) ? pv[e1][2] : 0.0f;
        w.w = (tp <= tau0 + 3) ? pv[e1][3] : 0.0f;
        *(f4*)&VT[tp * 64 + tau0] = w;
    }
    __syncthreads();

    // ---- phase 3: O_intra = P @ K ----
    float acc[4][4];
    #pragma unroll
    for (int a = 0; a < 4; ++a)
        #pragma unroll
        for (int b2 = 0; b2 < 4; ++b2) acc[a][b2] = 0.0f;
    for (int tp = 0; tp < 64; ++tp) {
        float p4[4], k4[4];
        LD4F(p4, &VT[tp * 64 + tau0]);
        LD4F(k4, &KsS[tp * 64 + 4 * (ig ^ (tp & 15))]);
        #pragma unroll
        for (int e0 = 0; e0 < 4; ++e0)
            #pragma unroll
            for (int e1 = 0; e1 < 4; ++e1) acc[e0][e1] += p4[e0] * k4[e1];
    }
    __syncthreads();

    // ---- stage Sp^T into VT space; wave0 builds in-place column cumsum of K ----
    #pragma unroll
    for (int ii = 0; ii < 4; ++ii) {
        int fi = t + ii * 256;
        int ir = fi >> 4;
        int j4 = fi & 15;
        f4 sv = *(const f4*)&Sp[bc * (kH * kH) + ir * kH + j4 * 4];
        VT[(j4 * 4 + 0) * 64 + ir] = sv.x;
        VT[(j4 * 4 + 1) * 64 + ir] = sv.y;
        VT[(j4 * 4 + 2) * 64 + ir] = sv.z;
        VT[(j4 * 4 + 3) * 64 + ir] = sv.w;
    }
    if (t < 64) {
        float run = 0.0f;
        const int jc4 = t >> 2, jr = t & 3;
        for (int tau = 0; tau < 64; ++tau) {
            int idx = tau * 64 + 4 * (jc4 ^ (tau & 15)) + jr;
            run += KsS[idx];
            KsS[idx] = run;
        }
    }
    __syncthreads();

    // ---- denominators (wave0): d[tau] = q_tau . (zp + CK[tau]) ----
    if (t < 64) {
        float dacc = 0.0f;
        for (int j = 0; j < 64; ++j) {
            float qv = QT[j * 64 + t];
            float ck = KsS[t * 64 + 4 * ((j >> 2) ^ (t & 15)) + (j & 3)];
            dacc += qv * (ck + zps[j]);
        }
        ds[t] = 1.0f / fmaxf(dacc, 1e-6f);
    }

    // ---- phase 4: O_inter = Q @ Sp^T ----
    for (int j = 0; j < 64; ++j) {
        float q4[4], s4[4];
        LD4F(q4, &QT[j * 64 + tau0]);
        LD4F(s4, &VT[j * 64 + ip0]);
        #pragma unroll
        for (int e0 = 0; e0 < 4; ++e0)
            #pragma unroll
            for (int e1 = 0; e1 < 4; ++e1) acc[e0][e1] += q4[e0] * s4[e1];
    }
    __syncthreads();

    // ---- normalize + write ----
    #pragma unroll
    for (int e0 = 0; e0 < 4; ++e0) {
        float inv = ds[tau0 + e0];
        f4 w;
        w.x = acc[e0][0] * inv; w.y = acc[e0][1] * inv;
        w.z = acc[e0][2] * inv; w.w = acc[e0][3] * inv;
        *(f4*)&o[(rowbase + tau0 + e0) * kH + ip0] = w;
    }
}

// ---------------------------------------------------------------------------
// K5: out = o @ W_o.  M=32768, K=64, N=1024.  LDS-free; per-thread 8x8 tile.
// grid = 256 (M/128) x 8 (N/128).
// ---------------------------------------------------------------------------
__global__ __launch_bounds__(256)
void k5_outproj(const float* __restrict__ o, const float* __restrict__ Wo,
                float* __restrict__ out)
{
    const int t  = threadIdx.x;
    const int mb = blockIdx.x >> 3;
    const int nb = blockIdx.x & 7;
    const int rg = t >> 4;
    const int cg = t & 15;
    const long row0 = (long)mb * 128 + rg * 8;
    const int  col0 = nb * 128 + cg * 4;

    float acc[8][2][4];
    #pragma unroll
    for (int r = 0; r < 8; ++r)
        #pragma unroll
        for (int g = 0; g < 2; ++g)
            #pragma unroll
            for (int c = 0; c < 4; ++c) acc[r][g][c] = 0.0f;

    for (int k4 = 0; k4 < 16; ++k4) {
        float ov[8][4];
        #pragma unroll
        for (int r = 0; r < 8; ++r) LD4F(ov[r], &o[(row0 + r) * kH + k4 * 4]);
        float wv[4][2][4];
        #pragma unroll
        for (int e = 0; e < 4; ++e) {
            LD4F(wv[e][0], &Wo[(long)(k4 * 4 + e) * kD + col0]);
            LD4F(wv[e][1], &Wo[(long)(k4 * 4 + e) * kD + col0 + 64]);
        }
        #pragma unroll
        for (int r = 0; r < 8; ++r)
            #pragma unroll
            for (int e = 0; e < 4; ++e)
                #pragma unroll
                for (int g = 0; g < 2; ++g)
                    #pragma unroll
                    for (int c = 0; c < 4; ++c)
                        acc[r][g][c] += ov[r][e] * wv[e][g][c];
    }
    #pragma unroll
    for (int r = 0; r < 8; ++r)
        #pragma unroll
        for (int g = 0; g < 2; ++g) {
            f4 w; w.x = acc[r][g][0]; w.y = acc[r][g][1];
            w.z = acc[r][g][2]; w.w = acc[r][g][3];
            *(f4*)&out[(row0 + r) * kD + col0 + g * 64] = w;
        }
}

// ---------------------------------------------------------------------------
extern "C" void kernel_launch(void* const* d_in, const int* in_sizes, int n_in,
                              void* d_out, int out_size, void* d_ws, size_t ws_size,
                              hipStream_t stream)
{
    const float* x  = (const float*)d_in[0];
    const float* Wq = (const float*)d_in[1];
    const float* Wk = (const float*)d_in[2];
    const float* Wv = (const float*)d_in[3];
    const float* Wo = (const float*)d_in[4];
    float* out = (float*)d_out;
    float* ws  = (float*)d_ws;

    // Workspace layout (floats); total ~50.6 MB.
    const long NQ = kBT * kH;            // 2097152
    float* q  = ws;
    float* k  = ws + NQ;
    float* v  = ws + 2 * NQ;
    float* o  = ws + 3 * NQ;
    float* Sc = ws + 4 * NQ;             // B*NC*H*H == NQ
    float* Sp = ws + 5 * NQ;
    float* zc = ws + 6 * NQ;             // B*NC*H = 32768
    float* zp = zc + (long)kB * kNC * kH;

    k1_qkv<<<256, 256, 0, stream>>>(x, Wq, Wk, Wv, q, k, v);
    k2_state<<<kB * kNC, 256, 0, stream>>>(k, v, Sc, zc);
    k3_prefix<<<130, 256, 0, stream>>>(Sc, Sp, zc, zp);
    k4_chunkout<<<kB * kNC, 256, 0, stream>>>(q, k, v, Sp, zp, o);
    k5_outproj<<<2048, 256, 0, stream>>>(o, Wo, out);
}

// Round 4
// 317.649 us; speedup vs baseline: 2.2237x; 2.2237x over previous
//
#include <hip/hip_runtime.h>
#include <math.h>

typedef float4 f4;
typedef __attribute__((ext_vector_type(4))) float f32x4;
typedef __attribute__((ext_vector_type(8))) short short8;
typedef __attribute__((ext_vector_type(4))) unsigned short u16x4;

static constexpr int kB  = 8;
static constexpr int kT  = 4096;
static constexpr int kD  = 1024;
static constexpr int kH  = 64;
static constexpr int kC  = 64;            // chunk length
static constexpr int kNC = kT / kC;       // 64 chunks per batch
static constexpr long kBT = (long)kB * kT;

__device__ __forceinline__ float phi_f(float x) {
    return x > 0.0f ? x + 1.0f : __expf(x);
}

__device__ __forceinline__ unsigned short f2bf(float f) {
    unsigned int u = __float_as_uint(f);
    u += 0x7FFF + ((u >> 16) & 1);        // round-to-nearest-even
    return (unsigned short)(u >> 16);
}

typedef const __attribute__((address_space(1))) unsigned int gu32;
typedef __attribute__((address_space(3))) unsigned int lu32;
#define GLL16(SRC, DST) __builtin_amdgcn_global_load_lds((gu32*)(SRC), (lu32*)(DST), 16, 0, 0)

#define LD4F(dst, src) { f4 _t_ = *(const f4*)(src); (dst)[0]=_t_.x; (dst)[1]=_t_.y; (dst)[2]=_t_.z; (dst)[3]=_t_.w; }

// ---------------------------------------------------------------------------
// K0: weight prep.  Wt[n=mat*64+nn][k] = W_mat[k][nn] (bf16, 192x1024)
//     Wot[n][k] = Wo[k][n]             (bf16, 1024x64)
// ---------------------------------------------------------------------------
__global__ __launch_bounds__(256)
void k0_prep(const float* __restrict__ Wq, const float* __restrict__ Wk,
             const float* __restrict__ Wv, const float* __restrict__ Wo,
             unsigned short* __restrict__ Wt, unsigned short* __restrict__ Wot)
{
    int g = blockIdx.x * 256 + threadIdx.x;
    if (g < 12288) {                       // 192 n-rows x 64 chunks of 16 k
        int n  = g >> 6;
        int kc = (g & 63) * 16;
        int mat = n >> 6, nn = n & 63;
        const float* W = (mat == 0) ? Wq : ((mat == 1) ? Wk : Wv);
        unsigned short* dst = Wt + (long)n * kD + kc;
        #pragma unroll
        for (int i = 0; i < 16; ++i) dst[i] = f2bf(W[(long)(kc + i) * kH + nn]);
    } else if (g < 12288 + 4096) {         // 1024 n-rows x 4 chunks of 16 k
        int g2 = g - 12288;
        int n  = g2 >> 2;
        int kc = (g2 & 3) * 16;
        unsigned short* dst = Wot + n * kH + kc;
        #pragma unroll
        for (int i = 0; i < 16; ++i) dst[i] = f2bf(Wo[(long)(kc + i) * kD + n]);
    }
}

// ---------------------------------------------------------------------------
// K1: q = phi(x Wq), k = phi(x Wk), v = x Wv via bf16 MFMA 16x16x32.
// BM=64, BN=192, BK=32. 256 thr = 4 waves; wave w: rows w*16..+16, all 12 n-frags.
// A: reg-staged fp32->bf16 (prefetched); B: global_load_lds w/ pre-swizzled src.
// ---------------------------------------------------------------------------
__global__ __launch_bounds__(256, 4)
void k1_qkv_mfma(const float* __restrict__ x, const unsigned short* __restrict__ Wt,
                 float* __restrict__ q, float* __restrict__ k, float* __restrict__ v)
{
    __shared__ unsigned short As[64 * 32];    // [row][chunk^(row&3)] chunks of 8 bf16
    __shared__ unsigned short Bs[192 * 32];   // linear dest; src pre-swizzled

    const int t = threadIdx.x;
    const int w = t >> 6;
    const int l = t & 63;
    const long mb = (long)blockIdx.x * 64;

    f32x4 acc[12];
    #pragma unroll
    for (int i = 0; i < 12; ++i) acc[i] = (f32x4){0.f, 0.f, 0.f, 0.f};

    // A staging map: thread t -> row t>>2, chunk t&3 (8 floats -> 8 bf16)
    const int arow = t >> 2;
    const int ach  = t & 3;
    const float* aptr = x + (mb + arow) * kD + ach * 8;
    unsigned short* adst = As + arow * 32 + ((ach ^ (arow & 3)) * 8);

    // B staging map (per global_load_lds call c): r = (c*4+w)*16 + (l>>2)
    const int brow_in = l >> 2;
    const int bch     = l & 3;

    // A-fragment read address (fixed): row = w*16 + (l&15)
    const int am_row = w * 16 + (l & 15);
    const unsigned short* afp = As + am_row * 32 + (((l >> 4) ^ (am_row & 3)) * 8);

    f32x4 a0 = *(const f32x4*)aptr;
    f32x4 a1 = *(const f32x4*)(aptr + 4);

    for (int k0 = 0; k0 < kD; k0 += 32) {
        // stage B tile (12KB) via 3 wave-level direct-to-LDS loads
        #pragma unroll
        for (int c = 0; c < 3; ++c) {
            int r = (c * 4 + w) * 16 + brow_in;
            int g = bch ^ (r & 3);
            GLL16(Wt + (long)r * kD + k0 + g * 8, Bs + (c * 4 + w) * 512);
        }
        // stage A tile: cvt current regs -> LDS
        short8 ab;
        ab[0] = (short)f2bf(a0[0]); ab[1] = (short)f2bf(a0[1]);
        ab[2] = (short)f2bf(a0[2]); ab[3] = (short)f2bf(a0[3]);
        ab[4] = (short)f2bf(a1[0]); ab[5] = (short)f2bf(a1[1]);
        ab[6] = (short)f2bf(a1[2]); ab[7] = (short)f2bf(a1[3]);
        *(short8*)adst = ab;
        // prefetch next A tile
        if (k0 + 32 < kD) {
            a0 = *(const f32x4*)(aptr + k0 + 32);
            a1 = *(const f32x4*)(aptr + k0 + 36);
        }
        __syncthreads();

        short8 af = *(const short8*)afp;
        #pragma unroll
        for (int n16 = 0; n16 < 12; ++n16) {
            int r = n16 * 16 + (l & 15);
            short8 bf = *(const short8*)(Bs + r * 32 + (((l >> 4) ^ (r & 3)) * 8));
            acc[n16] = __builtin_amdgcn_mfma_f32_16x16x32_bf16(af, bf, acc[n16], 0, 0, 0);
        }
        __syncthreads();
    }

    // epilogue: D row = (l>>4)*4 + reg, col = l&15
    const int om = (l >> 4) * 4;
    #pragma unroll
    for (int n16 = 0; n16 < 12; ++n16) {
        int mat = n16 >> 2;
        int col = (n16 & 3) * 16 + (l & 15);
        float* outp = (mat == 0) ? q : ((mat == 1) ? k : v);
        #pragma unroll
        for (int reg = 0; reg < 4; ++reg) {
            long row = mb + w * 16 + om + reg;
            float val = acc[n16][reg];
            if (mat < 2) val = phi_f(val);
            outp[row * kH + col] = val;
        }
    }
}

// ---------------------------------------------------------------------------
// K2: per-chunk state  Sc[i][j] = sum_tau k[tau][i] v[tau][j],  zc[i] = sum k.
// ---------------------------------------------------------------------------
__global__ __launch_bounds__(256)
void k2_state(const float* __restrict__ k, const float* __restrict__ v,
              float* __restrict__ Sc, float* __restrict__ zc)
{
    __shared__ float Ks2[64][64];
    __shared__ float Vs2[64][64];
    const int t = threadIdx.x;
    const long bc = blockIdx.x;
    const long rowbase = bc * kC;

    #pragma unroll
    for (int i = 0; i < 4; ++i) {
        int fi  = t + i * 256;
        int tau = fi >> 4;
        int cc  = (fi & 15) * 4;
        *(f4*)&Ks2[tau][cc] = *(const f4*)&k[(rowbase + tau) * kH + cc];
        *(f4*)&Vs2[tau][cc] = *(const f4*)&v[(rowbase + tau) * kH + cc];
    }
    __syncthreads();

    const int i  = t >> 2;
    const int j0 = (t & 3) * 16;
    float acc[16];
    #pragma unroll
    for (int c = 0; c < 16; ++c) acc[c] = 0.0f;
    float zacc = 0.0f;

    for (int tau = 0; tau < 64; ++tau) {
        float kv = Ks2[tau][i];
        zacc += kv;
        #pragma unroll
        for (int c = 0; c < 4; ++c) {
            float vv[4];
            LD4F(vv, &Vs2[tau][j0 + c * 4]);
            #pragma unroll
            for (int e = 0; e < 4; ++e) acc[c * 4 + e] += kv * vv[e];
        }
    }
    float* scp = Sc + bc * (kH * kH) + i * kH + j0;
    #pragma unroll
    for (int c = 0; c < 4; ++c) {
        f4 val; val.x = acc[c*4]; val.y = acc[c*4+1]; val.z = acc[c*4+2]; val.w = acc[c*4+3];
        *(f4*)&scp[c * 4] = val;
    }
    if ((t & 3) == 0) zc[bc * kH + i] = zacc;
}

// ---------------------------------------------------------------------------
// K3: exclusive prefix over chunks.
// ---------------------------------------------------------------------------
__global__ __launch_bounds__(256)
void k3_prefix(const float* __restrict__ Sc, float* __restrict__ Sp,
               const float* __restrict__ zc, float* __restrict__ zp)
{
    const int t = threadIdx.x;
    const int blk = blockIdx.x;
    if (blk < 128) {
        int g = blk * 256 + t;
        int b = g >> 12;
        int rem = g & 4095;
        const float* src = Sc + (long)b * kNC * kH * kH + rem;
        float*       dst = Sp + (long)b * kNC * kH * kH + rem;
        float vals[kNC];
        #pragma unroll
        for (int c = 0; c < kNC; ++c) vals[c] = src[c * (kH * kH)];
        float run = 0.0f;
        #pragma unroll
        for (int c = 0; c < kNC; ++c) { float nv = vals[c]; vals[c] = run; run += nv; }
        #pragma unroll
        for (int c = 0; c < kNC; ++c) dst[c * (kH * kH)] = vals[c];
    } else {
        int g = (blk - 128) * 256 + t;
        int b = g >> 6;
        int i = g & 63;
        const float* src = zc + (long)b * kNC * kH + i;
        float*       dst = zp + (long)b * kNC * kH + i;
        float vals[kNC];
        #pragma unroll
        for (int c = 0; c < kNC; ++c) vals[c] = src[c * kH];
        float run = 0.0f;
        #pragma unroll
        for (int c = 0; c < kNC; ++c) { float nv = vals[c]; vals[c] = run; run += nv; }
        #pragma unroll
        for (int c = 0; c < kNC; ++c) dst[c * kH] = vals[c];
    }
}

// ---------------------------------------------------------------------------
// K4: per-chunk output (unchanged algebra); now emits o in bf16.
// ---------------------------------------------------------------------------
__global__ __launch_bounds__(256)
void k4_chunkout(const float* __restrict__ q, const float* __restrict__ k,
                 const float* __restrict__ v, const float* __restrict__ Sp,
                 const float* __restrict__ zp, unsigned short* __restrict__ o)
{
    __shared__ float QT[64 * 64];
    __shared__ float KsS[64 * 64];
    __shared__ float VT[64 * 64];
    __shared__ float zps[64];
    __shared__ float ds[64];

    const int t = threadIdx.x;
    const long bc = blockIdx.x;
    const long rowbase = bc * kC;

    #pragma unroll
    for (int ii = 0; ii < 4; ++ii) {
        int fi  = t + ii * 256;
        int tau = fi >> 4;
        int c4  = fi & 15;
        f4 qv = *(const f4*)&q[(rowbase + tau) * kH + c4 * 4];
        QT[(c4 * 4 + 0) * 64 + tau] = qv.x;
        QT[(c4 * 4 + 1) * 64 + tau] = qv.y;
        QT[(c4 * 4 + 2) * 64 + tau] = qv.z;
        QT[(c4 * 4 + 3) * 64 + tau] = qv.w;
        f4 vv = *(const f4*)&v[(rowbase + tau) * kH + c4 * 4];
        VT[(c4 * 4 + 0) * 64 + tau] = vv.x;
        VT[(c4 * 4 + 1) * 64 + tau] = vv.y;
        VT[(c4 * 4 + 2) * 64 + tau] = vv.z;
        VT[(c4 * 4 + 3) * 64 + tau] = vv.w;
        f4 kv = *(const f4*)&k[(rowbase + tau) * kH + c4 * 4];
        *(f4*)&KsS[tau * 64 + 4 * (c4 ^ (tau & 15))] = kv;
    }
    if (t < 16) {
        *(f4*)&zps[t * 4] = *(const f4*)&zp[bc * kH + t * 4];
    }
    __syncthreads();

    const int tg   = t & 15;
    const int ig   = t >> 4;
    const int tau0 = tg * 4;
    const int ip0  = ig * 4;

    float pv[4][4];
    #pragma unroll
    for (int a = 0; a < 4; ++a)
        #pragma unroll
        for (int b2 = 0; b2 < 4; ++b2) pv[a][b2] = 0.0f;
    for (int xx = 0; xx < 64; ++xx) {
        float q4[4], v4[4];
        LD4F(q4, &QT[xx * 64 + tau0]);
        LD4F(v4, &VT[xx * 64 + ip0]);
        #pragma unroll
        for (int e1 = 0; e1 < 4; ++e1)
            #pragma unroll
            for (int e0 = 0; e0 < 4; ++e0) pv[e1][e0] += v4[e1] * q4[e0];
    }
    __syncthreads();
    #pragma unroll
    for (int e1 = 0; e1 < 4; ++e1) {
        int tp = ip0 + e1;
        f4 w;
        w.x = (tp <= tau0 + 0) ? pv[e1][0] : 0.0f;
        w.y = (tp <= tau0 + 1) ? pv[e1][1] : 0.0f;
        w.z = (tp <= tau0 + 2) ? pv[e1][2] : 0.0f;
        w.w = (tp <= tau0 + 3) ? pv[e1][3] : 0.0f;
        *(f4*)&VT[tp * 64 + tau0] = w;
    }
    __syncthreads();

    float acc[4][4];
    #pragma unroll
    for (int a = 0; a < 4; ++a)
        #pragma unroll
        for (int b2 = 0; b2 < 4; ++b2) acc[a][b2] = 0.0f;
    for (int tp = 0; tp < 64; ++tp) {
        float p4[4], k4[4];
        LD4F(p4, &VT[tp * 64 + tau0]);
        LD4F(k4, &KsS[tp * 64 + 4 * (ig ^ (tp & 15))]);
        #pragma unroll
        for (int e0 = 0; e0 < 4; ++e0)
            #pragma unroll
            for (int e1 = 0; e1 < 4; ++e1) acc[e0][e1] += p4[e0] * k4[e1];
    }
    __syncthreads();

    #pragma unroll
    for (int ii = 0; ii < 4; ++ii) {
        int fi = t + ii * 256;
        int ir = fi >> 4;
        int j4 = fi & 15;
        f4 sv = *(const f4*)&Sp[bc * (kH * kH) + ir * kH + j4 * 4];
        VT[(j4 * 4 + 0) * 64 + ir] = sv.x;
        VT[(j4 * 4 + 1) * 64 + ir] = sv.y;
        VT[(j4 * 4 + 2) * 64 + ir] = sv.z;
        VT[(j4 * 4 + 3) * 64 + ir] = sv.w;
    }
    if (t < 64) {
        float run = 0.0f;
        const int jc4 = t >> 2, jr = t & 3;
        for (int tau = 0; tau < 64; ++tau) {
            int idx = tau * 64 + 4 * (jc4 ^ (tau & 15)) + jr;
            run += KsS[idx];
            KsS[idx] = run;
        }
    }
    __syncthreads();

    if (t < 64) {
        float dacc = 0.0f;
        for (int j = 0; j < 64; ++j) {
            float qv = QT[j * 64 + t];
            float ck = KsS[t * 64 + 4 * ((j >> 2) ^ (t & 15)) + (j & 3)];
            dacc += qv * (ck + zps[j]);
        }
        ds[t] = 1.0f / fmaxf(dacc, 1e-6f);
    }

    for (int j = 0; j < 64; ++j) {
        float q4[4], s4[4];
        LD4F(q4, &QT[j * 64 + tau0]);
        LD4F(s4, &VT[j * 64 + ip0]);
        #pragma unroll
        for (int e0 = 0; e0 < 4; ++e0)
            #pragma unroll
            for (int e1 = 0; e1 < 4; ++e1) acc[e0][e1] += q4[e0] * s4[e1];
    }
    __syncthreads();

    #pragma unroll
    for (int e0 = 0; e0 < 4; ++e0) {
        float inv = ds[tau0 + e0];
        u16x4 wv;
        wv[0] = f2bf(acc[e0][0] * inv);
        wv[1] = f2bf(acc[e0][1] * inv);
        wv[2] = f2bf(acc[e0][2] * inv);
        wv[3] = f2bf(acc[e0][3] * inv);
        *(u16x4*)&o[(rowbase + tau0 + e0) * kH + ip0] = wv;
    }
}

// ---------------------------------------------------------------------------
// K5: out = o @ Wo via bf16 MFMA.  BM=128, BN=128, K=64 (single pass).
// Both tiles via global_load_lds (pre-swizzled src). grid 256x8.
// ---------------------------------------------------------------------------
__global__ __launch_bounds__(256, 4)
void k5_outproj_mfma(const unsigned short* __restrict__ o,
                     const unsigned short* __restrict__ Wot,
                     float* __restrict__ out)
{
    __shared__ unsigned short Os[128 * 64];
    __shared__ unsigned short Ws5[128 * 64];
    const int t = threadIdx.x;
    const int w = t >> 6, l = t & 63;
    const int wm = w >> 1, wn = w & 1;
    const int mb = blockIdx.x >> 3;
    const int nb = blockIdx.x & 7;
    const long row0 = (long)mb * 128;
    const int  col0 = nb * 128;

    const int rin = l >> 3;      // 0..7 row within 8-row group
    const int cch = l & 7;       // chunk 0..7
    #pragma unroll
    for (int c = 0; c < 4; ++c) {
        int r = (c * 4 + w) * 8 + rin;                 // 0..127
        int g = cch ^ (r & 7);
        GLL16(o   + (row0 + r) * kH + g * 8,        Os  + (c * 4 + w) * 512);
        GLL16(Wot + (long)(col0 + r) * kH + g * 8,  Ws5 + (c * 4 + w) * 512);
    }
    __syncthreads();

    short8 af[4][2];
    #pragma unroll
    for (int mf = 0; mf < 4; ++mf) {
        int ar = wm * 64 + mf * 16 + (l & 15);
        #pragma unroll
        for (int ks = 0; ks < 2; ++ks)
            af[mf][ks] = *(const short8*)(Os + ar * 64 + (((ks * 4 + (l >> 4)) ^ (ar & 7)) * 8));
    }

    f32x4 acc[4][4];
    #pragma unroll
    for (int a = 0; a < 4; ++a)
        #pragma unroll
        for (int b2 = 0; b2 < 4; ++b2) acc[a][b2] = (f32x4){0.f, 0.f, 0.f, 0.f};

    #pragma unroll
    for (int nf = 0; nf < 4; ++nf) {
        int br = wn * 64 + nf * 16 + (l & 15);
        short8 bf0 = *(const short8*)(Ws5 + br * 64 + ((((l >> 4)) ^ (br & 7)) * 8));
        short8 bf1 = *(const short8*)(Ws5 + br * 64 + (((4 + (l >> 4)) ^ (br & 7)) * 8));
        #pragma unroll
        for (int mf = 0; mf < 4; ++mf) {
            acc[mf][nf] = __builtin_amdgcn_mfma_f32_16x16x32_bf16(af[mf][0], bf0, acc[mf][nf], 0, 0, 0);
            acc[mf][nf] = __builtin_amdgcn_mfma_f32_16x16x32_bf16(af[mf][1], bf1, acc[mf][nf], 0, 0, 0);
        }
    }

    #pragma unroll
    for (int mf = 0; mf < 4; ++mf)
        #pragma unroll
        for (int nf = 0; nf < 4; ++nf) {
            #pragma unroll
            for (int reg = 0; reg < 4; ++reg) {
                long row = row0 + wm * 64 + mf * 16 + (l >> 4) * 4 + reg;
                int  col = col0 + wn * 64 + nf * 16 + (l & 15);
                out[row * kD + col] = acc[mf][nf][reg];
            }
        }
}

// ---------------------------------------------------------------------------
extern "C" void kernel_launch(void* const* d_in, const int* in_sizes, int n_in,
                              void* d_out, int out_size, void* d_ws, size_t ws_size,
                              hipStream_t stream)
{
    const float* x  = (const float*)d_in[0];
    const float* Wq = (const float*)d_in[1];
    const float* Wk = (const float*)d_in[2];
    const float* Wv = (const float*)d_in[3];
    const float* Wo = (const float*)d_in[4];
    float* out = (float*)d_out;
    float* ws  = (float*)d_ws;

    const long NQ = kBT * kH;                     // 2097152
    float* q  = ws;
    float* k  = ws + NQ;
    float* v  = ws + 2 * NQ;
    float* Sc = ws + 3 * NQ;
    float* Sp = ws + 4 * NQ;
    unsigned short* obf = (unsigned short*)(ws + 5 * NQ);        // NQ bf16
    float* zc = ws + 5 * NQ + NQ / 2;
    float* zp = zc + (long)kB * kNC * kH;
    unsigned short* Wt  = (unsigned short*)(zp + (long)kB * kNC * kH);  // 192*1024
    unsigned short* Wot = Wt + 192 * 1024;                              // 1024*64

    k0_prep<<<64, 256, 0, stream>>>(Wq, Wk, Wv, Wo, Wt, Wot);
    k1_qkv_mfma<<<512, 256, 0, stream>>>(x, Wt, q, k, v);
    k2_state<<<kB * kNC, 256, 0, stream>>>(k, v, Sc, zc);
    k3_prefix<<<130, 256, 0, stream>>>(Sc, Sp, zc, zp);
    k4_chunkout<<<kB * kNC, 256, 0, stream>>>(q, k, v, Sp, zp, obf);
    k5_outproj_mfma<<<2048, 256, 0, stream>>>(obf, Wot, out);
}